// Round 7
// baseline (3334.800 us; speedup 1.0000x reference)
//
#include <hip/hip_runtime.h>
#include <stdint.h>

// RNN_Stack: 3-layer leaky-integrator RNN, T=512, B=256, I=64, N=512, TAU=2.
//
// Round-7 = round-6 with fixed asm modifier order (offset: before sc1).
// Barrier-free wave-autonomous pipeline with SYNCHRONOUS batched sc1 loads:
// each 16-fragment ring read is ONE asm block (16x global_load_dwordx4 with
// immediate offsets + s_waitcnt vmcnt(0) inside), outputs early-clobber, so
// the compiler's value-ready-at-asm-end model matches HW and spills can never
// capture in-flight load garbage (the round-4/5 failure mode). q-frags are
// consumed before p-frags are issued to keep peak VGPR pressure < 256.
//   192 blocks = 3 layers x 16 rowgroups x 4 coltiles; 256 thr, 1 wave/SIMD.
//   No LDS, no __syncthreads in the step loop; wave-granular relaxed agent
//   flags; payload via sc1 (LLC coherence point) loads/stores; release =
//   vmcnt(0) drain before flag store, acquire = control dep on flag poll.

#define TS    512
#define BB    256
#define NN    512
#define MR    16     // rows per block
#define NRG   16     // rowgroups
#define NCT   4      // coltiles per layer
#define RD    8      // ring depth (steps)

typedef __attribute__((ext_vector_type(8))) short s8v;    // 8 bf16 (4 VGPR)
typedef __attribute__((ext_vector_type(4))) float f4v;    // 4 f32

#define MFMA16(a, b, c) __builtin_amdgcn_mfma_f32_16x16x32_bf16((a), (b), (c), 0, 0, 0)

__device__ __forceinline__ short f2bf(float f) {  // RNE f32 -> bf16 bits
  union { float f; unsigned u; } v; v.f = f;
  unsigned u = v.u;
  u += 0x7fffu + ((u >> 16) & 1u);
  return (short)(u >> 16);
}

__device__ __forceinline__ s8v pack8(f4v a, f4v b) {
  s8v v;
  v[0] = f2bf(a[0]); v[1] = f2bf(a[1]); v[2] = f2bf(a[2]); v[3] = f2bf(a[3]);
  v[4] = f2bf(b[0]); v[5] = f2bf(b[1]); v[6] = f2bf(b[2]); v[7] = f2bf(b[3]);
  return v;
}

// Synchronous batched sc1 load: 16x dwordx4 from base+kk*64B, completed
// before the asm block exits. Early-clobber outputs: no overlap with addr.
__device__ __forceinline__ void ld16_sync(s8v o[16], const unsigned short* p) {
  asm volatile(
      "global_load_dwordx4 %0,  %16, off sc1\n\t"
      "global_load_dwordx4 %1,  %16, off offset:64 sc1\n\t"
      "global_load_dwordx4 %2,  %16, off offset:128 sc1\n\t"
      "global_load_dwordx4 %3,  %16, off offset:192 sc1\n\t"
      "global_load_dwordx4 %4,  %16, off offset:256 sc1\n\t"
      "global_load_dwordx4 %5,  %16, off offset:320 sc1\n\t"
      "global_load_dwordx4 %6,  %16, off offset:384 sc1\n\t"
      "global_load_dwordx4 %7,  %16, off offset:448 sc1\n\t"
      "global_load_dwordx4 %8,  %16, off offset:512 sc1\n\t"
      "global_load_dwordx4 %9,  %16, off offset:576 sc1\n\t"
      "global_load_dwordx4 %10, %16, off offset:640 sc1\n\t"
      "global_load_dwordx4 %11, %16, off offset:704 sc1\n\t"
      "global_load_dwordx4 %12, %16, off offset:768 sc1\n\t"
      "global_load_dwordx4 %13, %16, off offset:832 sc1\n\t"
      "global_load_dwordx4 %14, %16, off offset:896 sc1\n\t"
      "global_load_dwordx4 %15, %16, off offset:960 sc1\n\t"
      "s_waitcnt vmcnt(0)"
      : "=&v"(o[0]), "=&v"(o[1]), "=&v"(o[2]), "=&v"(o[3]),
        "=&v"(o[4]), "=&v"(o[5]), "=&v"(o[6]), "=&v"(o[7]),
        "=&v"(o[8]), "=&v"(o[9]), "=&v"(o[10]), "=&v"(o[11]),
        "=&v"(o[12]), "=&v"(o[13]), "=&v"(o[14]), "=&v"(o[15])
      : "v"(p)
      : "memory");
}

__device__ __forceinline__ void stg_sc1_b16(unsigned short* p, unsigned v) {
  asm volatile("global_store_short %0, %1, off sc1" :: "v"(p), "v"(v) : "memory");
}
__device__ __forceinline__ void waitvm0() {
  asm volatile("s_waitcnt vmcnt(0)" ::: "memory");
}

__global__ __launch_bounds__(256, 1) void rnn_pipe(
    const float* __restrict__ data, const float* __restrict__ h0,
    const float* __restrict__ Win,  const float* __restrict__ b_in,
    const float* __restrict__ Whh,  const float* __restrict__ b_hh,
    const float* __restrict__ Whi,  const float* __restrict__ b_hi,
    unsigned short* __restrict__ ring, unsigned* __restrict__ cnt,
    float* __restrict__ hfinal)
{
  const int bi   = blockIdx.x;
  const int lay  = bi % 3;
  const int rest = bi / 3;        // 0..63
  const int rg   = rest & 15;
  const int ct   = rest >> 4;     // 0..3
  const int tid  = threadIdx.x;
  const int wv   = tid >> 6;
  const int lane = tid & 63;
  const int lo   = lane & 15;
  const int q4   = lane >> 4;
  const int row0 = rg * MR;
  const int cw   = ct * 128 + wv * 32;   // this wave's 32-col base
  const int wci  = ct * 4 + wv;          // wave-col index 0..15 in (lay,rg)

  // ---- wave-granular flags, 128B stride ----
  const int fq = (lay * NRG + rg) * 16;
  unsigned* myprod = cnt + (size_t)(fq + wci) * 32;
  unsigned* mydone = cnt + (size_t)(768 + fq + wci) * 32;

  unsigned* pollptr = myprod;   // dummy: always satisfied
  int polltype = 0;
  if (lane < 16) {                           // q-join: own (lay,rg) waves
    pollptr = cnt + (size_t)(fq + lane) * 32;  polltype = 1;
  } else if (lane < 32 && lay > 0) {         // p-join: upstream waves
    pollptr = cnt + (size_t)(((lay - 1) * NRG + rg) * 16 + (lane - 16)) * 32;  polltype = 2;
  } else if (lane >= 32 && lane < 48 && lay < 2) {   // backpressure: downstream done
    pollptr = cnt + (size_t)(768 + ((lay + 1) * NRG + rg) * 16 + (lane - 32)) * 32;  polltype = 3;
  }

  // ---- weight preload: B-frag[k = kk*32 + q4*8 + j][col = cw + nf*16 + lo] ----
  s8v WH[16][2];            // Whh_lay (diag zeroed)
  s8v WI[16][2];            // Whi_{lay-1} (lay>0)
  s8v WX[2][2];             // Win (K=64)
  float biasv[2];
  f4v  hst[2];              // f32 h-state, C-layout rows q4*4+r, cols cw+nf*16+lo

  {
    const float* WmH = Whh + (size_t)lay * NN * NN;
    #pragma unroll
    for (int kk = 0; kk < 16; ++kk) {
      #pragma unroll
      for (int nf = 0; nf < 2; ++nf) {
        const int col = cw + nf * 16 + lo;
        s8v v;
        #pragma unroll
        for (int j = 0; j < 8; ++j) {
          const int k = kk * 32 + q4 * 8 + j;
          float f = WmH[(size_t)k * NN + col];
          if (k == col) f = 0.f;            // forward() zeroes recurrent diag
          v[j] = f2bf(f);
        }
        WH[kk][nf] = v;
      }
    }
    if (lay > 0) {
      const float* WmI = Whi + (size_t)(lay - 1) * NN * NN;
      #pragma unroll
      for (int kk = 0; kk < 16; ++kk) {
        #pragma unroll
        for (int nf = 0; nf < 2; ++nf) {
          const int col = cw + nf * 16 + lo;
          s8v v;
          #pragma unroll
          for (int j = 0; j < 8; ++j)
            v[j] = f2bf(WmI[(size_t)(kk * 32 + q4 * 8 + j) * NN + col]);
          WI[kk][nf] = v;
        }
      }
    }
    #pragma unroll
    for (int kk = 0; kk < 2; ++kk) {
      #pragma unroll
      for (int nf = 0; nf < 2; ++nf) {
        const int col = cw + nf * 16 + lo;
        s8v v;
        #pragma unroll
        for (int j = 0; j < 8; ++j)
          v[j] = f2bf(Win[(size_t)(kk * 32 + q4 * 8 + j) * NN + col]);
        WX[kk][nf] = v;
      }
    }
    #pragma unroll
    for (int nf = 0; nf < 2; ++nf) {
      const int col = cw + nf * 16 + lo;
      float b = b_hh[lay * NN + col] + b_in[col];
      if (lay > 0) b += b_hi[(lay - 1) * NN + col];
      biasv[nf] = b;
      #pragma unroll
      for (int r = 0; r < 4; ++r)
        hst[nf][r] = h0[(size_t)lay * BB * NN + (size_t)(row0 + q4 * 4 + r) * NN + col];
    }
  }

  const size_t myring = (size_t)(lay * NRG + rg) * RD;
  const size_t upring = (size_t)((lay - 1) * NRG + rg) * RD;

  for (int t = 0; t < TS; ++t) {
    // ---- hoisted data(t) loads (latency hides under the poll) ----
    const float* dsrc = data + ((size_t)t * BB + row0 + lo) * 64 + q4 * 8;
    f4v xa0 = *(const f4v*)(dsrc + 0);
    f4v xa1 = *(const f4v*)(dsrc + 4);
    f4v xa2 = *(const f4v*)(dsrc + 32);
    f4v xa3 = *(const f4v*)(dsrc + 36);

    // ---- per-wave poll: all join conditions in parallel across lanes ----
    unsigned tgt = 0;
    if (polltype == 1) tgt = (unsigned)t;
    else if (polltype == 2) tgt = (unsigned)(t + 1);
    else if (polltype == 3 && t >= RD) tgt = (unsigned)(t - RD + 1);
    for (;;) {
      unsigned v = __hip_atomic_load(pollptr, __ATOMIC_RELAXED, __HIP_MEMORY_SCOPE_AGENT);
      if (__all((int)(v >= tgt))) break;
      __builtin_amdgcn_s_sleep(1);
    }

    // ---- x-part MFMAs ----
    f4v zero4 = {0.f, 0.f, 0.f, 0.f};
    f4v accQ[2] = {zero4, zero4};
    f4v accP[2] = {zero4, zero4};
    {
      s8v xv0 = pack8(xa0, xa1);
      s8v xv1 = pack8(xa2, xa3);
      accQ[0] = MFMA16(xv0, WX[0][0], accQ[0]);
      accQ[1] = MFMA16(xv0, WX[0][1], accQ[1]);
      accQ[0] = MFMA16(xv1, WX[1][0], accQ[0]);
      accQ[1] = MFMA16(xv1, WX[1][1], accQ[1]);
    }

    // ---- q-part: sync batched load, consume immediately (frees the batch) ----
    if (t >= 1) {
      s8v qa[16];
      const unsigned short* qsrc =
          ring + (myring + ((t - 1) & (RD - 1))) * (MR * NN) + (size_t)lo * NN + q4 * 8;
      ld16_sync(qa, qsrc);
      #pragma unroll
      for (int kk = 0; kk < 16; ++kk) {
        accQ[0] = MFMA16(qa[kk], WH[kk][0], accQ[0]);
        accQ[1] = MFMA16(qa[kk], WH[kk][1], accQ[1]);
      }
    } else {
      const float* hsrc = h0 + (size_t)lay * BB * NN + (size_t)(row0 + lo) * NN + q4 * 8;
      #pragma unroll
      for (int kk = 0; kk < 16; ++kk) {
        f4v a = *(const f4v*)(hsrc + kk * 32);
        f4v b = *(const f4v*)(hsrc + kk * 32 + 4);
        s8v av = pack8(a, b);
        accQ[0] = MFMA16(av, WH[kk][0], accQ[0]);
        accQ[1] = MFMA16(av, WH[kk][1], accQ[1]);
      }
    }

    // ---- p-part: sync batched load, publish done, consume ----
    if (lay > 0) {
      s8v pa[16];
      const unsigned short* psrc =
          ring + (upring + (t & (RD - 1))) * (MR * NN) + (size_t)lo * NN + q4 * 8;
      ld16_sync(pa, psrc);
      if (lane == 0)   // p data is in registers; upstream may overwrite slot t
        __hip_atomic_store(mydone, (unsigned)(t + 1), __ATOMIC_RELAXED,
                           __HIP_MEMORY_SCOPE_AGENT);
      #pragma unroll
      for (int kk = 0; kk < 16; ++kk) {
        accP[0] = MFMA16(pa[kk], WI[kk][0], accP[0]);
        accP[1] = MFMA16(pa[kk], WI[kk][1], accP[1]);
      }
    }

    // ---- combine + produce: n = lrelu(0.5*h + 0.5*(q+p+x+bias)) ----
    {
      unsigned short* rslot = ring + (myring + (t & (RD - 1))) * (MR * NN);
      #pragma unroll
      for (int nf = 0; nf < 2; ++nf) {
        const int col = cw + nf * 16 + lo;
        #pragma unroll
        for (int r = 0; r < 4; ++r) {
          const int row = q4 * 4 + r;
          float v = 0.5f * hst[nf][r] + 0.5f * (accQ[nf][r] + accP[nf][r] + biasv[nf]);
          v = (v >= 0.f) ? v : 0.01f * v;
          hst[nf][r] = v;
          stg_sc1_b16(rslot + (size_t)row * NN + col,
                      (unsigned)(unsigned short)f2bf(v));
          if (lay == 2 && t == TS - 1)
            hfinal[(size_t)(row0 + row) * NN + col] = v;
        }
      }
    }
    waitvm0();   // this wave's payload stores drained to the coherence point
    if (lane == 0)
      __hip_atomic_store(myprod, (unsigned)(t + 1), __ATOMIC_RELAXED,
                         __HIP_MEMORY_SCOPE_AGENT);
  }
}

// out[256,10] = hfinal @ Wfc + b_fc   (tiny f32 readout)
__global__ void readout_k(const float* __restrict__ hfinal, const float* __restrict__ Wfc,
                          const float* __restrict__ b_fc, float* __restrict__ out)
{
  const int row = blockIdx.x;
  const int lane = threadIdx.x;  // 64
  float a[10];
  #pragma unroll
  for (int c = 0; c < 10; ++c) a[c] = 0.f;
  for (int k = lane; k < NN; k += 64) {
    const float h = hfinal[(size_t)row * NN + k];
    const float* w = Wfc + (size_t)k * 10;
    #pragma unroll
    for (int c = 0; c < 10; ++c) a[c] += h * w[c];
  }
  #pragma unroll
  for (int off = 32; off > 0; off >>= 1) {
    #pragma unroll
    for (int c = 0; c < 10; ++c) a[c] += __shfl_down(a[c], off);
  }
  if (lane == 0) {
    #pragma unroll
    for (int c = 0; c < 10; ++c) out[row * 10 + c] = a[c] + b_fc[c];
  }
}

extern "C" void kernel_launch(void* const* d_in, const int* in_sizes, int n_in,
                              void* d_out, int out_size, void* d_ws, size_t ws_size,
                              hipStream_t stream) {
  (void)in_sizes; (void)n_in; (void)out_size; (void)ws_size;
  const float* data = (const float*)d_in[0];
  const float* h0   = (const float*)d_in[1];
  const float* Win  = (const float*)d_in[2];
  const float* b_in = (const float*)d_in[3];
  const float* Whh  = (const float*)d_in[4];
  const float* b_hh = (const float*)d_in[5];
  const float* Whi  = (const float*)d_in[6];
  const float* b_hi = (const float*)d_in[7];
  const float* Wfc  = (const float*)d_in[8];
  const float* b_fc = (const float*)d_in[9];

  // ws: rings (3 lay x 16 rg x RD x 16KB = 6 MB) | flags 256KB | hfinal 512KB
  unsigned short* ring = (unsigned short*)d_ws;
  const size_t ring_bytes = (size_t)3 * NRG * RD * MR * NN * 2;  // 6 MB
  unsigned* cnt = (unsigned*)((char*)d_ws + ring_bytes);
  float* hfinal = (float*)((char*)d_ws + ring_bytes + 262144);

  hipMemsetAsync(cnt, 0, 262144, stream);   // flags MUST start at 0 (ws is poisoned)
  hipLaunchKernelGGL(rnn_pipe, dim3(192), dim3(256), 0, stream,
                     data, h0, Win, b_in, Whh, b_hh, Whi, b_hi, ring, cnt, hfinal);
  hipLaunchKernelGGL(readout_k, dim3(256), dim3(64), 0, stream,
                     hfinal, Wfc, b_fc, (float*)d_out);
}

// Round 8
// 2338.651 us; speedup vs baseline: 1.4260x; 1.4260x over previous
//
#include <hip/hip_runtime.h>
#include <stdint.h>

// RNN_Stack: 3-layer leaky-integrator RNN, T=512, B=256, I=64, N=512, TAU=2.
//
// Round-8 = round-3 (cooperative LDS staging, block-level flags, 2 barriers)
// with the post-poll critical chain stripped:
//   - x = data @ Win computed BEFORE the poll; data(t+1) loads issued before
//     the store-drain waitvm0 of step t (latency hidden under the drain).
//   - staging is ONE sync asm block (q+p merged: 8x global_load_dwordx4 sc1
//     with immediate offsets + s_waitcnt vmcnt(0) inside, early-clobber
//     outputs) -> single LLC round trip, spill-safe by construction.
//   - per-block tile staged ONCE (5 MB/step LLC traffic vs r7's 20 MB).
//   192 blocks = 3 layers x 16 rowgroups x 4 coltiles; 256 thr, 1 wave/SIMD.

#define TS    512
#define BB    256
#define NN    512
#define MR    16     // rows per block
#define NRG   16     // rowgroups
#define NCT   4      // coltiles per layer
#define RD    8      // ring depth (steps)
#define LROW  520    // padded LDS row stride (shorts)

typedef __attribute__((ext_vector_type(8))) short s8v;    // 8 bf16 (4 VGPR)
typedef __attribute__((ext_vector_type(4))) float f4v;    // 4 f32
typedef __attribute__((ext_vector_type(4))) unsigned int u4v;

#define MFMA16(a, b, c) __builtin_amdgcn_mfma_f32_16x16x32_bf16((a), (b), (c), 0, 0, 0)

__device__ __forceinline__ short f2bf(float f) {  // RNE f32 -> bf16 bits
  union { float f; unsigned u; } v; v.f = f;
  unsigned u = v.u;
  u += 0x7fffu + ((u >> 16) & 1u);
  return (short)(u >> 16);
}

__device__ __forceinline__ s8v pack8(f4v a, f4v b) {
  s8v v;
  v[0] = f2bf(a[0]); v[1] = f2bf(a[1]); v[2] = f2bf(a[2]); v[3] = f2bf(a[3]);
  v[4] = f2bf(b[0]); v[5] = f2bf(b[1]); v[6] = f2bf(b[2]); v[7] = f2bf(b[3]);
  return v;
}

// Sync batched sc1 loads (complete before the asm block exits; early-clobber
// outputs so spills can never capture in-flight data). 64B per thread per base.
__device__ __forceinline__ void ld8_sync(u4v o[8], const unsigned short* qp,
                                         const unsigned short* pp) {
  asm volatile(
      "global_load_dwordx4 %0, %8, off sc1\n\t"
      "global_load_dwordx4 %1, %8, off offset:16 sc1\n\t"
      "global_load_dwordx4 %2, %8, off offset:32 sc1\n\t"
      "global_load_dwordx4 %3, %8, off offset:48 sc1\n\t"
      "global_load_dwordx4 %4, %9, off sc1\n\t"
      "global_load_dwordx4 %5, %9, off offset:16 sc1\n\t"
      "global_load_dwordx4 %6, %9, off offset:32 sc1\n\t"
      "global_load_dwordx4 %7, %9, off offset:48 sc1\n\t"
      "s_waitcnt vmcnt(0)"
      : "=&v"(o[0]), "=&v"(o[1]), "=&v"(o[2]), "=&v"(o[3]),
        "=&v"(o[4]), "=&v"(o[5]), "=&v"(o[6]), "=&v"(o[7])
      : "v"(qp), "v"(pp)
      : "memory");
}
__device__ __forceinline__ void ld4_sync(u4v o[4], const unsigned short* p) {
  asm volatile(
      "global_load_dwordx4 %0, %4, off sc1\n\t"
      "global_load_dwordx4 %1, %4, off offset:16 sc1\n\t"
      "global_load_dwordx4 %2, %4, off offset:32 sc1\n\t"
      "global_load_dwordx4 %3, %4, off offset:48 sc1\n\t"
      "s_waitcnt vmcnt(0)"
      : "=&v"(o[0]), "=&v"(o[1]), "=&v"(o[2]), "=&v"(o[3])
      : "v"(p)
      : "memory");
}

__device__ __forceinline__ void stg_sc1_b16(unsigned short* p, unsigned v) {
  asm volatile("global_store_short %0, %1, off sc1" :: "v"(p), "v"(v) : "memory");
}
__device__ __forceinline__ void waitvm0() {
  asm volatile("s_waitcnt vmcnt(0)" ::: "memory");
}

__global__ __launch_bounds__(256, 1) void rnn_pipe(
    const float* __restrict__ data, const float* __restrict__ h0,
    const float* __restrict__ Win,  const float* __restrict__ b_in,
    const float* __restrict__ Whh,  const float* __restrict__ b_hh,
    const float* __restrict__ Whi,  const float* __restrict__ b_hi,
    unsigned short* __restrict__ ring, unsigned* __restrict__ cnt,
    float* __restrict__ hfinal)
{
  __shared__ __attribute__((aligned(16))) unsigned short qtile[MR * LROW];
  __shared__ __attribute__((aligned(16))) unsigned short ptile[MR * LROW];

  const int bi   = blockIdx.x;
  const int lay  = bi % 3;
  const int rest = bi / 3;        // 0..63
  const int rg   = rest & 15;
  const int ct   = rest >> 4;     // 0..3
  const int tid  = threadIdx.x;
  const int wv   = tid >> 6;
  const int lane = tid & 63;
  const int lo   = lane & 15;
  const int q4   = lane >> 4;
  const int row0 = rg * MR;
  const int cw   = ct * 128 + wv * 32;   // this wave's 32-col base

  // ---- flags: prod[idx], done[idx] at 128B stride; idx=(lay*16+rg)*4+ct ----
  const int sidx = (lay * NRG + rg) * NCT + ct;
  unsigned* selfprod = cnt + (size_t)sidx * 32;
  unsigned* selfdone = cnt + (size_t)(256 + sidx) * 32;

  // per-lane poll assignment (lanes 0-3: q-join, 4-7: p-join, 8-11: backpressure)
  unsigned* pollptr = selfprod;   // dummy (target stays satisfied)
  int polltype = 0;
  if (lane < 4) {
    pollptr = cnt + (size_t)((lay * NRG + rg) * NCT + lane) * 32;  polltype = 1;
  } else if (lane >= 4 && lane < 8 && lay > 0) {
    pollptr = cnt + (size_t)(((lay - 1) * NRG + rg) * NCT + (lane - 4)) * 32;  polltype = 2;
  } else if (lane >= 8 && lane < 12 && lay < 2) {
    pollptr = cnt + (size_t)(256 + ((lay + 1) * NRG + rg) * NCT + (lane - 8)) * 32;  polltype = 3;
  }

  // ---- weight preload: B-frag[k = kk*32 + q4*8 + j][col = cw + nf*16 + lo] ----
  s8v WH[16][2];            // Whh_lay (diag zeroed)
  s8v WI[16][2];            // Whi_{lay-1} (lay>0)
  s8v WX[2][2];             // Win (K=64)
  float biasv[2];
  f4v  hst[2];              // f32 h-state, C-layout rows q4*4+r, cols cw+nf*16+lo

  {
    const float* WmH = Whh + (size_t)lay * NN * NN;
    #pragma unroll
    for (int kk = 0; kk < 16; ++kk) {
      #pragma unroll
      for (int nf = 0; nf < 2; ++nf) {
        const int col = cw + nf * 16 + lo;
        s8v v;
        #pragma unroll
        for (int j = 0; j < 8; ++j) {
          const int k = kk * 32 + q4 * 8 + j;
          float f = WmH[(size_t)k * NN + col];
          if (k == col) f = 0.f;            // forward() zeroes recurrent diag
          v[j] = f2bf(f);
        }
        WH[kk][nf] = v;
      }
    }
    if (lay > 0) {
      const float* WmI = Whi + (size_t)(lay - 1) * NN * NN;
      #pragma unroll
      for (int kk = 0; kk < 16; ++kk) {
        #pragma unroll
        for (int nf = 0; nf < 2; ++nf) {
          const int col = cw + nf * 16 + lo;
          s8v v;
          #pragma unroll
          for (int j = 0; j < 8; ++j)
            v[j] = f2bf(WmI[(size_t)(kk * 32 + q4 * 8 + j) * NN + col]);
          WI[kk][nf] = v;
        }
      }
    }
    #pragma unroll
    for (int kk = 0; kk < 2; ++kk) {
      #pragma unroll
      for (int nf = 0; nf < 2; ++nf) {
        const int col = cw + nf * 16 + lo;
        s8v v;
        #pragma unroll
        for (int j = 0; j < 8; ++j)
          v[j] = f2bf(Win[(size_t)(kk * 32 + q4 * 8 + j) * NN + col]);
        WX[kk][nf] = v;
      }
    }
    #pragma unroll
    for (int nf = 0; nf < 2; ++nf) {
      const int col = cw + nf * 16 + lo;
      float b = b_hh[lay * NN + col] + b_in[col];
      if (lay > 0) b += b_hi[(lay - 1) * NN + col];
      biasv[nf] = b;
      #pragma unroll
      for (int r = 0; r < 4; ++r)
        hst[nf][r] = h0[(size_t)lay * BB * NN + (size_t)(row0 + q4 * 4 + r) * NN + col];
    }
  }

  const size_t myring = (size_t)(lay * NRG + rg) * RD;
  const size_t upring = (size_t)((lay - 1) * NRG + rg) * RD;

  // ---- xa preload for t=0 ----
  f4v xa0, xa1, xa2, xa3;
  {
    const float* dsrc = data + ((size_t)0 * BB + row0 + lo) * 64 + q4 * 8;
    xa0 = *(const f4v*)(dsrc + 0);
    xa1 = *(const f4v*)(dsrc + 4);
    xa2 = *(const f4v*)(dsrc + 32);
    xa3 = *(const f4v*)(dsrc + 36);
  }

  for (int t = 0; t < TS; ++t) {
    // ---- x-part MFMAs BEFORE the poll (xa loaded under previous drain) ----
    f4v zero4 = {0.f, 0.f, 0.f, 0.f};
    f4v acc[2] = {zero4, zero4};
    {
      s8v xv0 = pack8(xa0, xa1);
      s8v xv1 = pack8(xa2, xa3);
      acc[0] = MFMA16(xv0, WX[0][0], acc[0]);
      acc[1] = MFMA16(xv0, WX[0][1], acc[1]);
      acc[0] = MFMA16(xv1, WX[1][0], acc[0]);
      acc[1] = MFMA16(xv1, WX[1][1], acc[1]);
    }

    // ---- poll all join conditions in parallel across lanes ----
    unsigned tgt = 0;
    if (polltype == 1) tgt = (unsigned)t;                                  // q-join
    else if (polltype == 2) tgt = (unsigned)(t + 1);                       // p-join
    else if (polltype == 3 && t >= RD) tgt = (unsigned)(t - RD + 1);       // backpressure
    for (;;) {
      unsigned v = __hip_atomic_load(pollptr, __ATOMIC_RELAXED, __HIP_MEMORY_SCOPE_AGENT);
      if (__all((int)(v >= tgt))) break;
    }

    // ---- cooperative staging: ONE sync asm block, 64B/thread/tile ----
    // chunk c = tid*4+i -> LDS row c>>6, 16B-col c&63 (coalesced 16KB/tile)
    {
      const unsigned short* qsrc =
          ring + (myring + ((t - 1) & (RD - 1))) * (MR * NN) + (size_t)tid * 32;
      const unsigned short* psrc =
          ring + (upring + (t & (RD - 1))) * (MR * NN) + (size_t)tid * 32;
      u4v st[8];
      if (t >= 1 && lay > 0) {
        ld8_sync(st, qsrc, psrc);
        #pragma unroll
        for (int i = 0; i < 4; ++i) {
          const int c = tid * 4 + i;
          *(u4v*)(qtile + (c >> 6) * LROW + (c & 63) * 8) = st[i];
          *(u4v*)(ptile + (c >> 6) * LROW + (c & 63) * 8) = st[4 + i];
        }
      } else if (t >= 1) {
        ld4_sync(st, qsrc);
        #pragma unroll
        for (int i = 0; i < 4; ++i) {
          const int c = tid * 4 + i;
          *(u4v*)(qtile + (c >> 6) * LROW + (c & 63) * 8) = st[i];
        }
      } else if (lay > 0) {
        ld4_sync(st, psrc);
        #pragma unroll
        for (int i = 0; i < 4; ++i) {
          const int c = tid * 4 + i;
          *(u4v*)(ptile + (c >> 6) * LROW + (c & 63) * 8) = st[i];
        }
      }
    }
    __syncthreads();   // staging visible to all waves
    if (tid == 0 && lay > 0)   // upstream slot t consumed into LDS
      __hip_atomic_store(selfdone, (unsigned)(t + 1), __ATOMIC_RELAXED,
                         __HIP_MEMORY_SCOPE_AGENT);

    // ---- MFMA phase: q + p from LDS (t=0 q from h0) ----
    if (lay > 0) {
      #pragma unroll
      for (int kk = 0; kk < 16; ++kk) {
        s8v av = *(const s8v*)(ptile + lo * LROW + kk * 32 + q4 * 8);
        acc[0] = MFMA16(av, WI[kk][0], acc[0]);
        acc[1] = MFMA16(av, WI[kk][1], acc[1]);
      }
    }
    if (t == 0) {
      const float* hsrc = h0 + (size_t)lay * BB * NN + (size_t)(row0 + lo) * NN + q4 * 8;
      #pragma unroll
      for (int kk = 0; kk < 16; ++kk) {
        f4v a = *(const f4v*)(hsrc + kk * 32);
        f4v b = *(const f4v*)(hsrc + kk * 32 + 4);
        s8v av = pack8(a, b);
        acc[0] = MFMA16(av, WH[kk][0], acc[0]);
        acc[1] = MFMA16(av, WH[kk][1], acc[1]);
      }
    } else {
      #pragma unroll
      for (int kk = 0; kk < 16; ++kk) {
        s8v av = *(const s8v*)(qtile + lo * LROW + kk * 32 + q4 * 8);
        acc[0] = MFMA16(av, WH[kk][0], acc[0]);
        acc[1] = MFMA16(av, WH[kk][1], acc[1]);
      }
    }

    // ---- combine + produce: n = lrelu(0.5*h + 0.5*(q+p+x+bias)) ----
    {
      unsigned short* rslot = ring + (myring + (t & (RD - 1))) * (MR * NN);
      #pragma unroll
      for (int nf = 0; nf < 2; ++nf) {
        const int col = cw + nf * 16 + lo;
        #pragma unroll
        for (int r = 0; r < 4; ++r) {
          const int row = q4 * 4 + r;
          float v = 0.5f * hst[nf][r] + 0.5f * (acc[nf][r] + biasv[nf]);
          v = (v >= 0.f) ? v : 0.01f * v;
          hst[nf][r] = v;
          stg_sc1_b16(rslot + (size_t)row * NN + col,
                      (unsigned)(unsigned short)f2bf(v));
          if (lay == 2 && t == TS - 1)
            hfinal[(size_t)(row0 + row) * NN + col] = v;
        }
      }
    }

    // ---- xa loads for t+1 (latency hidden under the store drain) ----
    {
      const int tn = (t + 1 < TS) ? t + 1 : t;
      const float* dsrc = data + ((size_t)tn * BB + row0 + lo) * 64 + q4 * 8;
      xa0 = *(const f4v*)(dsrc + 0);
      xa1 = *(const f4v*)(dsrc + 4);
      xa2 = *(const f4v*)(dsrc + 32);
      xa3 = *(const f4v*)(dsrc + 36);
    }
    waitvm0();         // drains payload stores (and xa loads)
    __syncthreads();   // every wave's stores drained -> publish
    if (tid == 0)
      __hip_atomic_store(selfprod, (unsigned)(t + 1), __ATOMIC_RELAXED,
                         __HIP_MEMORY_SCOPE_AGENT);
  }
}

// out[256,10] = hfinal @ Wfc + b_fc   (tiny f32 readout)
__global__ void readout_k(const float* __restrict__ hfinal, const float* __restrict__ Wfc,
                          const float* __restrict__ b_fc, float* __restrict__ out)
{
  const int row = blockIdx.x;
  const int lane = threadIdx.x;  // 64
  float a[10];
  #pragma unroll
  for (int c = 0; c < 10; ++c) a[c] = 0.f;
  for (int k = lane; k < NN; k += 64) {
    const float h = hfinal[(size_t)row * NN + k];
    const float* w = Wfc + (size_t)k * 10;
    #pragma unroll
    for (int c = 0; c < 10; ++c) a[c] += h * w[c];
  }
  #pragma unroll
  for (int off = 32; off > 0; off >>= 1) {
    #pragma unroll
    for (int c = 0; c < 10; ++c) a[c] += __shfl_down(a[c], off);
  }
  if (lane == 0) {
    #pragma unroll
    for (int c = 0; c < 10; ++c) out[row * 10 + c] = a[c] + b_fc[c];
  }
}

extern "C" void kernel_launch(void* const* d_in, const int* in_sizes, int n_in,
                              void* d_out, int out_size, void* d_ws, size_t ws_size,
                              hipStream_t stream) {
  (void)in_sizes; (void)n_in; (void)out_size; (void)ws_size;
  const float* data = (const float*)d_in[0];
  const float* h0   = (const float*)d_in[1];
  const float* Win  = (const float*)d_in[2];
  const float* b_in = (const float*)d_in[3];
  const float* Whh  = (const float*)d_in[4];
  const float* b_hh = (const float*)d_in[5];
  const float* Whi  = (const float*)d_in[6];
  const float* b_hi = (const float*)d_in[7];
  const float* Wfc  = (const float*)d_in[8];
  const float* b_fc = (const float*)d_in[9];

  // ws: rings (3 lay x 16 rg x RD x 16KB = 6 MB) | flags 64KB | hfinal 512KB
  unsigned short* ring = (unsigned short*)d_ws;
  const size_t ring_bytes = (size_t)3 * NRG * RD * MR * NN * 2;  // 6 MB
  unsigned* cnt = (unsigned*)((char*)d_ws + ring_bytes);
  float* hfinal = (float*)((char*)d_ws + ring_bytes + 65536);

  hipMemsetAsync(cnt, 0, 65536, stream);   // flags MUST start at 0 (ws is poisoned)
  hipLaunchKernelGGL(rnn_pipe, dim3(192), dim3(256), 0, stream,
                     data, h0, Win, b_in, Whh, b_hh, Whi, b_hi, ring, cnt, hfinal);
  hipLaunchKernelGGL(readout_k, dim3(256), dim3(64), 0, stream,
                     hfinal, Wfc, b_fc, (float*)d_out);
}

// Round 9
// 2239.751 us; speedup vs baseline: 1.4889x; 1.0442x over previous
//
#include <hip/hip_runtime.h>
#include <stdint.h>

// RNN_Stack: 3-layer leaky-integrator RNN, T=512, B=256, I=64, N=512, TAU=2.
//
// Round-9 = round-8 skeleton (cooperative staging, block flags, 2 barriers,
// x-part pre-poll, sync asm sc1 loads) with the LDS pipe unblocked:
//   - XOR-swizzled LDS tiles: chunk c of row r lives at c^(r&7). Staging
//     writes and A-frag ds_read_b128 both become 2-way (free) instead of
//     8-way; LDS row stride 1024B (no pad needed; swizzle does the work).
//   - staging loads are DENSE: chunk g=i*256+tid -> each load instr covers a
//     contiguous 1KB per wave (saddr-form global_load_dwordx4 ... sc1).
//   - 4 accumulator chains (accQ/accP x 2 col-frags): MFMA chain 32->16 deep.
//   192 blocks = 3 layers x 16 rowgroups x 4 coltiles; 256 thr, 1 wave/SIMD.

#define TS    512
#define BB    256
#define NN    512
#define MR    16     // rows per block
#define NRG   16     // rowgroups
#define NCT   4      // coltiles per layer
#define RD    8      // ring depth (steps)

// swizzled short-index of 16B-chunk c (0..63) in row r (0..15)
#define SW(r, c) (((r) << 9) + ((((c) ^ ((r) & 7))) << 3))

typedef __attribute__((ext_vector_type(8))) short s8v;    // 8 bf16 (4 VGPR)
typedef __attribute__((ext_vector_type(4))) float f4v;    // 4 f32
typedef __attribute__((ext_vector_type(4))) unsigned int u4v;

#define MFMA16(a, b, c) __builtin_amdgcn_mfma_f32_16x16x32_bf16((a), (b), (c), 0, 0, 0)

__device__ __forceinline__ short f2bf(float f) {  // RNE f32 -> bf16 bits
  union { float f; unsigned u; } v; v.f = f;
  unsigned u = v.u;
  u += 0x7fffu + ((u >> 16) & 1u);
  return (short)(u >> 16);
}

__device__ __forceinline__ s8v pack8(f4v a, f4v b) {
  s8v v;
  v[0] = f2bf(a[0]); v[1] = f2bf(a[1]); v[2] = f2bf(a[2]); v[3] = f2bf(a[3]);
  v[4] = f2bf(b[0]); v[5] = f2bf(b[1]); v[6] = f2bf(b[2]); v[7] = f2bf(b[3]);
  return v;
}

// Sync batched sc1 loads, saddr form: dense 1KB/wave per instruction.
// Completed before the asm block exits (early-clobber outs; spill-safe).
__device__ __forceinline__ void ld8_sync(u4v o[8],
    unsigned v0, unsigned v1, unsigned v2, unsigned v3,
    const unsigned short* sq, const unsigned short* sp) {
  asm volatile(
      "global_load_dwordx4 %0, %8, %12 sc1\n\t"
      "global_load_dwordx4 %1, %9, %12 sc1\n\t"
      "global_load_dwordx4 %2, %10, %12 sc1\n\t"
      "global_load_dwordx4 %3, %11, %12 sc1\n\t"
      "global_load_dwordx4 %4, %8, %13 sc1\n\t"
      "global_load_dwordx4 %5, %9, %13 sc1\n\t"
      "global_load_dwordx4 %6, %10, %13 sc1\n\t"
      "global_load_dwordx4 %7, %11, %13 sc1\n\t"
      "s_waitcnt vmcnt(0)"
      : "=&v"(o[0]), "=&v"(o[1]), "=&v"(o[2]), "=&v"(o[3]),
        "=&v"(o[4]), "=&v"(o[5]), "=&v"(o[6]), "=&v"(o[7])
      : "v"(v0), "v"(v1), "v"(v2), "v"(v3), "s"(sq), "s"(sp)
      : "memory");
}
__device__ __forceinline__ void ld4_sync(u4v o[4],
    unsigned v0, unsigned v1, unsigned v2, unsigned v3,
    const unsigned short* sb) {
  asm volatile(
      "global_load_dwordx4 %0, %4, %8 sc1\n\t"
      "global_load_dwordx4 %1, %5, %8 sc1\n\t"
      "global_load_dwordx4 %2, %6, %8 sc1\n\t"
      "global_load_dwordx4 %3, %7, %8 sc1\n\t"
      "s_waitcnt vmcnt(0)"
      : "=&v"(o[0]), "=&v"(o[1]), "=&v"(o[2]), "=&v"(o[3])
      : "v"(v0), "v"(v1), "v"(v2), "v"(v3), "s"(sb)
      : "memory");
}

__device__ __forceinline__ void stg_sc1_b16(unsigned short* p, unsigned v) {
  asm volatile("global_store_short %0, %1, off sc1" :: "v"(p), "v"(v) : "memory");
}
__device__ __forceinline__ void waitvm0() {
  asm volatile("s_waitcnt vmcnt(0)" ::: "memory");
}

__global__ __launch_bounds__(256, 1) void rnn_pipe(
    const float* __restrict__ data, const float* __restrict__ h0,
    const float* __restrict__ Win,  const float* __restrict__ b_in,
    const float* __restrict__ Whh,  const float* __restrict__ b_hh,
    const float* __restrict__ Whi,  const float* __restrict__ b_hi,
    unsigned short* __restrict__ ring, unsigned* __restrict__ cnt,
    float* __restrict__ hfinal)
{
  __shared__ __attribute__((aligned(16))) unsigned short qtile[MR * NN];
  __shared__ __attribute__((aligned(16))) unsigned short ptile[MR * NN];

  const int bi   = blockIdx.x;
  const int lay  = bi % 3;
  const int rest = bi / 3;        // 0..63
  const int rg   = rest & 15;
  const int ct   = rest >> 4;     // 0..3
  const int tid  = threadIdx.x;
  const int wv   = tid >> 6;
  const int lane = tid & 63;
  const int lo   = lane & 15;
  const int q4   = lane >> 4;
  const int row0 = rg * MR;
  const int cw   = ct * 128 + wv * 32;   // this wave's 32-col base

  // ---- flags: prod[idx], done[idx] at 128B stride; idx=(lay*16+rg)*4+ct ----
  const int sidx = (lay * NRG + rg) * NCT + ct;
  unsigned* selfprod = cnt + (size_t)sidx * 32;
  unsigned* selfdone = cnt + (size_t)(256 + sidx) * 32;

  // per-lane poll assignment (lanes 0-3: q-join, 4-7: p-join, 8-11: backpressure)
  unsigned* pollptr = selfprod;   // dummy (target stays satisfied)
  int polltype = 0;
  if (lane < 4) {
    pollptr = cnt + (size_t)((lay * NRG + rg) * NCT + lane) * 32;  polltype = 1;
  } else if (lane >= 4 && lane < 8 && lay > 0) {
    pollptr = cnt + (size_t)(((lay - 1) * NRG + rg) * NCT + (lane - 4)) * 32;  polltype = 2;
  } else if (lane >= 8 && lane < 12 && lay < 2) {
    pollptr = cnt + (size_t)(256 + ((lay + 1) * NRG + rg) * NCT + (lane - 8)) * 32;  polltype = 3;
  }

  // ---- weight preload: B-frag[k = kk*32 + q4*8 + j][col = cw + nf*16 + lo] ----
  s8v WH[16][2];            // Whh_lay (diag zeroed)
  s8v WI[16][2];            // Whi_{lay-1} (lay>0)
  s8v WX[2][2];             // Win (K=64)
  float biasv[2];
  f4v  hst[2];              // f32 h-state, C-layout rows q4*4+r, cols cw+nf*16+lo

  {
    const float* WmH = Whh + (size_t)lay * NN * NN;
    #pragma unroll
    for (int kk = 0; kk < 16; ++kk) {
      #pragma unroll
      for (int nf = 0; nf < 2; ++nf) {
        const int col = cw + nf * 16 + lo;
        s8v v;
        #pragma unroll
        for (int j = 0; j < 8; ++j) {
          const int k = kk * 32 + q4 * 8 + j;
          float f = WmH[(size_t)k * NN + col];
          if (k == col) f = 0.f;            // forward() zeroes recurrent diag
          v[j] = f2bf(f);
        }
        WH[kk][nf] = v;
      }
    }
    if (lay > 0) {
      const float* WmI = Whi + (size_t)(lay - 1) * NN * NN;
      #pragma unroll
      for (int kk = 0; kk < 16; ++kk) {
        #pragma unroll
        for (int nf = 0; nf < 2; ++nf) {
          const int col = cw + nf * 16 + lo;
          s8v v;
          #pragma unroll
          for (int j = 0; j < 8; ++j)
            v[j] = f2bf(WmI[(size_t)(kk * 32 + q4 * 8 + j) * NN + col]);
          WI[kk][nf] = v;
        }
      }
    }
    #pragma unroll
    for (int kk = 0; kk < 2; ++kk) {
      #pragma unroll
      for (int nf = 0; nf < 2; ++nf) {
        const int col = cw + nf * 16 + lo;
        s8v v;
        #pragma unroll
        for (int j = 0; j < 8; ++j)
          v[j] = f2bf(Win[(size_t)(kk * 32 + q4 * 8 + j) * NN + col]);
        WX[kk][nf] = v;
      }
    }
    #pragma unroll
    for (int nf = 0; nf < 2; ++nf) {
      const int col = cw + nf * 16 + lo;
      float b = b_hh[lay * NN + col] + b_in[col];
      if (lay > 0) b += b_hi[(lay - 1) * NN + col];
      biasv[nf] = b;
      #pragma unroll
      for (int r = 0; r < 4; ++r)
        hst[nf][r] = h0[(size_t)lay * BB * NN + (size_t)(row0 + q4 * 4 + r) * NN + col];
    }
  }

  const size_t myring = (size_t)(lay * NRG + rg) * RD;
  const size_t upring = (size_t)((lay - 1) * NRG + rg) * RD;

  // loop-invariant staging byte-offsets: chunk g = i*256 + tid (dense 1KB/wave)
  unsigned voff0 = (unsigned)((0 * 256 + tid) * 16);
  unsigned voff1 = (unsigned)((1 * 256 + tid) * 16);
  unsigned voff2 = (unsigned)((2 * 256 + tid) * 16);
  unsigned voff3 = (unsigned)((3 * 256 + tid) * 16);

  // ---- xa preload for t=0 ----
  f4v xa0, xa1, xa2, xa3;
  {
    const float* dsrc = data + ((size_t)0 * BB + row0 + lo) * 64 + q4 * 8;
    xa0 = *(const f4v*)(dsrc + 0);
    xa1 = *(const f4v*)(dsrc + 4);
    xa2 = *(const f4v*)(dsrc + 32);
    xa3 = *(const f4v*)(dsrc + 36);
  }

  for (int t = 0; t < TS; ++t) {
    // ---- x-part MFMAs BEFORE the poll (xa loaded under previous drain) ----
    f4v zero4 = {0.f, 0.f, 0.f, 0.f};
    f4v accQ[2] = {zero4, zero4};
    f4v accP[2] = {zero4, zero4};
    {
      s8v xv0 = pack8(xa0, xa1);
      s8v xv1 = pack8(xa2, xa3);
      accQ[0] = MFMA16(xv0, WX[0][0], accQ[0]);
      accQ[1] = MFMA16(xv0, WX[0][1], accQ[1]);
      accQ[0] = MFMA16(xv1, WX[1][0], accQ[0]);
      accQ[1] = MFMA16(xv1, WX[1][1], accQ[1]);
    }

    // ---- poll all join conditions in parallel across lanes ----
    unsigned tgt = 0;
    if (polltype == 1) tgt = (unsigned)t;                                  // q-join
    else if (polltype == 2) tgt = (unsigned)(t + 1);                       // p-join
    else if (polltype == 3 && t >= RD) tgt = (unsigned)(t - RD + 1);       // backpressure
    for (;;) {
      unsigned v = __hip_atomic_load(pollptr, __ATOMIC_RELAXED, __HIP_MEMORY_SCOPE_AGENT);
      if (__all((int)(v >= tgt))) break;
    }

    // ---- cooperative staging: ONE sync asm block, swizzled LDS writes ----
    {
      const unsigned short* qsrc = ring + (myring + ((t - 1) & (RD - 1))) * (MR * NN);
      const unsigned short* psrc = ring + (upring + (t & (RD - 1))) * (MR * NN);
      u4v st[8];
      if (t >= 1 && lay > 0) {
        ld8_sync(st, voff0, voff1, voff2, voff3, qsrc, psrc);
        #pragma unroll
        for (int i = 0; i < 4; ++i) {
          const int g = i * 256 + tid;
          const int r = g >> 6, c = g & 63;
          *(u4v*)(qtile + SW(r, c)) = st[i];
          *(u4v*)(ptile + SW(r, c)) = st[4 + i];
        }
      } else if (t >= 1) {
        ld4_sync(st, voff0, voff1, voff2, voff3, qsrc);
        #pragma unroll
        for (int i = 0; i < 4; ++i) {
          const int g = i * 256 + tid;
          const int r = g >> 6, c = g & 63;
          *(u4v*)(qtile + SW(r, c)) = st[i];
        }
      } else if (lay > 0) {
        ld4_sync(st, voff0, voff1, voff2, voff3, psrc);
        #pragma unroll
        for (int i = 0; i < 4; ++i) {
          const int g = i * 256 + tid;
          const int r = g >> 6, c = g & 63;
          *(u4v*)(ptile + SW(r, c)) = st[i];
        }
      }
    }
    __syncthreads();   // staging visible to all waves
    if (tid == 0 && lay > 0)   // upstream slot t consumed into LDS
      __hip_atomic_store(selfdone, (unsigned)(t + 1), __ATOMIC_RELAXED,
                         __HIP_MEMORY_SCOPE_AGENT);

    // ---- MFMA phase: q + p from swizzled LDS (t=0 q from h0) ----
    if (lay > 0) {
      #pragma unroll
      for (int kk = 0; kk < 16; ++kk) {
        s8v av = *(const s8v*)(ptile + SW(lo, kk * 4 + q4));
        accP[0] = MFMA16(av, WI[kk][0], accP[0]);
        accP[1] = MFMA16(av, WI[kk][1], accP[1]);
      }
    }
    if (t == 0) {
      const float* hsrc = h0 + (size_t)lay * BB * NN + (size_t)(row0 + lo) * NN + q4 * 8;
      #pragma unroll
      for (int kk = 0; kk < 16; ++kk) {
        f4v a = *(const f4v*)(hsrc + kk * 32);
        f4v b = *(const f4v*)(hsrc + kk * 32 + 4);
        s8v av = pack8(a, b);
        accQ[0] = MFMA16(av, WH[kk][0], accQ[0]);
        accQ[1] = MFMA16(av, WH[kk][1], accQ[1]);
      }
    } else {
      #pragma unroll
      for (int kk = 0; kk < 16; ++kk) {
        s8v av = *(const s8v*)(qtile + SW(lo, kk * 4 + q4));
        accQ[0] = MFMA16(av, WH[kk][0], accQ[0]);
        accQ[1] = MFMA16(av, WH[kk][1], accQ[1]);
      }
    }

    // ---- combine + produce: n = lrelu(0.5*h + 0.5*(q+p+x+bias)) ----
    {
      unsigned short* rslot = ring + (myring + (t & (RD - 1))) * (MR * NN);
      #pragma unroll
      for (int nf = 0; nf < 2; ++nf) {
        const int col = cw + nf * 16 + lo;
        #pragma unroll
        for (int r = 0; r < 4; ++r) {
          const int row = q4 * 4 + r;
          float v = 0.5f * hst[nf][r] + 0.5f * (accQ[nf][r] + accP[nf][r] + biasv[nf]);
          v = (v >= 0.f) ? v : 0.01f * v;
          hst[nf][r] = v;
          stg_sc1_b16(rslot + (size_t)row * NN + col,
                      (unsigned)(unsigned short)f2bf(v));
          if (lay == 2 && t == TS - 1)
            hfinal[(size_t)(row0 + row) * NN + col] = v;
        }
      }
    }

    // ---- xa loads for t+1 (latency hidden under the store drain) ----
    {
      const int tn = (t + 1 < TS) ? t + 1 : t;
      const float* dsrc = data + ((size_t)tn * BB + row0 + lo) * 64 + q4 * 8;
      xa0 = *(const f4v*)(dsrc + 0);
      xa1 = *(const f4v*)(dsrc + 4);
      xa2 = *(const f4v*)(dsrc + 32);
      xa3 = *(const f4v*)(dsrc + 36);
    }
    waitvm0();         // drains payload stores (and xa loads)
    __syncthreads();   // every wave's stores drained -> publish
    if (tid == 0)
      __hip_atomic_store(selfprod, (unsigned)(t + 1), __ATOMIC_RELAXED,
                         __HIP_MEMORY_SCOPE_AGENT);
  }
}

// out[256,10] = hfinal @ Wfc + b_fc   (tiny f32 readout)
__global__ void readout_k(const float* __restrict__ hfinal, const float* __restrict__ Wfc,
                          const float* __restrict__ b_fc, float* __restrict__ out)
{
  const int row = blockIdx.x;
  const int lane = threadIdx.x;  // 64
  float a[10];
  #pragma unroll
  for (int c = 0; c < 10; ++c) a[c] = 0.f;
  for (int k = lane; k < NN; k += 64) {
    const float h = hfinal[(size_t)row * NN + k];
    const float* w = Wfc + (size_t)k * 10;
    #pragma unroll
    for (int c = 0; c < 10; ++c) a[c] += h * w[c];
  }
  #pragma unroll
  for (int off = 32; off > 0; off >>= 1) {
    #pragma unroll
    for (int c = 0; c < 10; ++c) a[c] += __shfl_down(a[c], off);
  }
  if (lane == 0) {
    #pragma unroll
    for (int c = 0; c < 10; ++c) out[row * 10 + c] = a[c] + b_fc[c];
  }
}

extern "C" void kernel_launch(void* const* d_in, const int* in_sizes, int n_in,
                              void* d_out, int out_size, void* d_ws, size_t ws_size,
                              hipStream_t stream) {
  (void)in_sizes; (void)n_in; (void)out_size; (void)ws_size;
  const float* data = (const float*)d_in[0];
  const float* h0   = (const float*)d_in[1];
  const float* Win  = (const float*)d_in[2];
  const float* b_in = (const float*)d_in[3];
  const float* Whh  = (const float*)d_in[4];
  const float* b_hh = (const float*)d_in[5];
  const float* Whi  = (const float*)d_in[6];
  const float* b_hi = (const float*)d_in[7];
  const float* Wfc  = (const float*)d_in[8];
  const float* b_fc = (const float*)d_in[9];

  // ws: rings (3 lay x 16 rg x RD x 16KB = 6 MB) | flags 64KB | hfinal 512KB
  unsigned short* ring = (unsigned short*)d_ws;
  const size_t ring_bytes = (size_t)3 * NRG * RD * MR * NN * 2;  // 6 MB
  unsigned* cnt = (unsigned*)((char*)d_ws + ring_bytes);
  float* hfinal = (float*)((char*)d_ws + ring_bytes + 65536);

  hipMemsetAsync(cnt, 0, 65536, stream);   // flags MUST start at 0 (ws is poisoned)
  hipLaunchKernelGGL(rnn_pipe, dim3(192), dim3(256), 0, stream,
                     data, h0, Win, b_in, Whh, b_hh, Whi, b_hi, ring, cnt, hfinal);
  hipLaunchKernelGGL(readout_k, dim3(256), dim3(64), 0, stream,
                     hfinal, Wfc, b_fc, (float*)d_out);
}